// Round 7
// baseline (295.132 us; speedup 1.0000x reference)
//
#include <hip/hip_runtime.h>
#include <hip/hip_bf16.h>

typedef __bf16 bf16;
typedef __attribute__((ext_vector_type(8))) __bf16 bf16x8;
typedef __attribute__((ext_vector_type(4))) __bf16 bf16x4;
typedef __attribute__((ext_vector_type(4))) float f32x4;
typedef __attribute__((ext_vector_type(4))) short short4v;

// ---------------------------------------------------------------- constants
#define B_SZ 2
#define S_SZ 2048
#define D_SZ 2048
#define H_SZ 32
#define KV_SZ 8
#define HD_SZ 64
#define M_SZ (B_SZ * S_SZ)   // 4096
#define NQKV 3072            // 2048 Q + 512 K + 512 V packed weight rows

// async global->LDS, 16B per lane; LDS dest = wave-uniform base + lane*16
#define GLDS(g, s) __builtin_amdgcn_global_load_lds( \
    (const __attribute__((address_space(1))) void*)(g), \
    (__attribute__((address_space(3))) void*)(s), 16, 0, 0)

// lgkm-only barrier: do NOT drain vmcnt (global prefetch stays in flight
// across the barrier -- the vmcnt wait happens at the ds_write that consumes
// the loaded regs, a full pass after issue).
__device__ __forceinline__ void bar_lgkm() {
    asm volatile("s_waitcnt lgkmcnt(0)\n\ts_barrier" ::: "memory");
}

// 16x16x16 bf16 MFMA (K=16, 4 bf16/lane operands). B k-layout = quad*4+i,
// which exactly matches the x32 C-layout rows -> P feeds PV from registers.
#if defined(__has_builtin)
#if __has_builtin(__builtin_amdgcn_mfma_f32_16x16x16bf16_1k)
#define HAVE_MFMA16 1
#endif
#endif
__device__ __forceinline__ f32x4 mfma16(bf16x4 a, bf16x4 b, f32x4 c) {
#ifdef HAVE_MFMA16
    return __builtin_amdgcn_mfma_f32_16x16x16bf16_1k(
        __builtin_bit_cast(short4v, a), __builtin_bit_cast(short4v, b), c, 0, 0, 0);
#else
    asm("v_mfma_f32_16x16x16_bf16 %0, %1, %2, %0" : "+v"(c) : "v"(a), "v"(b));
    return c;
#endif
}

// ---------------------------------------------------------------- fused conversions
// single dispatch: x -> xb, [Wq;Wk;Wv] -> Wf, Wo -> wob (all bf16)
__global__ void cvt_all(const float* __restrict__ x, const float* __restrict__ Wq,
                        const float* __restrict__ Wk, const float* __restrict__ Wv,
                        const float* __restrict__ Wo,
                        bf16* __restrict__ xb, bf16* __restrict__ Wf, bf16* __restrict__ wob,
                        int nx, int n1, int n2) {
    int i = blockIdx.x * blockDim.x + threadIdx.x;
    const float* src; bf16* dst; int off;
    if (i < nx)                 { src = x;  dst = xb; off = i; }
    else {
        int j = i - nx;
        if (j < n1)             { src = Wq; dst = Wf; off = j; }
        else if (j < n1 + n2)   { src = Wk; dst = Wf + (size_t)4 * n1; off = j - n1; }
        else if (j < n1 + 2*n2) { src = Wv; dst = Wf + (size_t)4 * (n1 + n2); off = j - n1 - n2; }
        else if (j < 2*n1+2*n2) { src = Wo; dst = wob; off = j - n1 - 2 * n2; }
        else return;
    }
    float4 v = ((const float4*)src)[off];
    bf16x4 o;
    o.x = (bf16)v.x; o.y = (bf16)v.y; o.z = (bf16)v.z; o.w = (bf16)v.w;
    ((bf16x4*)dst)[off] = o;
}

// ---------------------------------------------------------------- GEMM core (m97 shape)
// 256 threads / 4 waves. Wave wv = (wr,wc) owns the 64x64 quadrant at
// (wr*64, wc*64); acc[4][4] of 16x16 frags.
// LDS: XOR-swizzled contiguous [128][64] tiles (glds-compatible): 16B chunk q
// of row r lives at chunk q^(r&7). Staging lane l fetches global chunk
// (l&7)^(l>>3) so the LDS write is linear; frag b128 reads conflict-free.
#define GEMM_CORE4(A_, B_, Kdim)                                                 \
    const int tid  = threadIdx.x;                                                \
    const int wv   = tid >> 6;                                                   \
    const int lane = tid & 63;                                                   \
    const int c = lane & 15, quad = lane >> 4;                                   \
    const int wr = wv >> 1, wc = wv & 1;                                         \
    const int g8 = lane >> 3;                                                    \
    const int chs = ((lane & 7) ^ g8) * 8;                                       \
    const int rowBase = blockIdx.y * 128;                                        \
    const int colBase = blockIdx.x * 128;                                        \
    const bf16* Ag = A_ + (size_t)(rowBase + wv * 32 + g8) * Kdim + chs;         \
    const bf16* Bg = B_ + (size_t)(colBase + wv * 32 + g8) * Kdim + chs;         \
    bf16* sAw = As + (wv * 32) * 64;                                             \
    bf16* sBw = Bs + (wv * 32) * 64;                                             \
    f32x4 acc[4][4] = {};                                                        \
    for (int k0 = 0; k0 < Kdim; k0 += 64) {                                      \
        _Pragma("unroll")                                                        \
        for (int j = 0; j < 4; j++) {                                            \
            GLDS(Ag + (size_t)(j * 8) * Kdim + k0, sAw + j * 512);               \
            GLDS(Bg + (size_t)(j * 8) * Kdim + k0, sBw + j * 512);               \
        }                                                                        \
        __syncthreads();                                                         \
        _Pragma("unroll")                                                        \
        for (int ks = 0; ks < 2; ks++) {                                         \
            bf16x8 af[4], bfr[4];                                                \
            _Pragma("unroll")                                                    \
            for (int mi = 0; mi < 4; mi++)                                       \
                af[mi] = *(const bf16x8*)(As + (wr * 64 + mi * 16 + c) * 64      \
                                          + (((ks << 2) + quad) ^ (c & 7)) * 8); \
            _Pragma("unroll")                                                    \
            for (int ni = 0; ni < 4; ni++)                                       \
                bfr[ni] = *(const bf16x8*)(Bs + (wc * 64 + ni * 16 + c) * 64     \
                                          + (((ks << 2) + quad) ^ (c & 7)) * 8); \
            _Pragma("unroll")                                                    \
            for (int mi = 0; mi < 4; mi++)                                       \
                _Pragma("unroll")                                                \
                for (int ni = 0; ni < 4; ni++)                                   \
                    acc[mi][ni] = __builtin_amdgcn_mfma_f32_16x16x32_bf16(       \
                        af[mi], bfr[ni], acc[mi][ni], 0, 0, 0);                  \
        }                                                                        \
        __syncthreads();                                                         \
    }                                                                            \
    const int mBase = rowBase + wr * 64;                                         \
    const int nBase = colBase + wc * 64;

// ---------------------------------------------------------------- fused QKV GEMM
__global__ __launch_bounds__(256, 2)
void gemm_qkv(const bf16* __restrict__ A, const bf16* __restrict__ Bw,
              bf16* __restrict__ Qb, bf16* __restrict__ Kb, bf16* __restrict__ Vtb,
              const float* __restrict__ cosp, const float* __restrict__ sinp,
              float qscale)
{
    __shared__ __align__(16) bf16 As[128 * 64];
    __shared__ __align__(16) bf16 Bs[128 * 64];

    GEMM_CORE4(A, Bw, D_SZ)

    // wave's 64 cols = exactly one 64-wide head; Q/K/V regions are 64-aligned
    const int hcol = nBase;
    if (hcol < 2560) {
        // ---- RoPE path (Q or K)
        bf16* dst; int hh, Hn; float sc;
        if (hcol < 2048) { dst = Qb; hh = hcol >> 6;        Hn = H_SZ;  sc = qscale; }
        else             { dst = Kb; hh = (hcol >> 6) - 32; Hn = KV_SZ; sc = 1.0f;  }
#pragma unroll
        for (int mi = 0; mi < 4; mi++) {
#pragma unroll
            for (int r = 0; r < 4; r++) {
                int row = mBase + mi * 16 + quad * 4 + r;
                int b = row >> 11;           // S = 2048
                int s = row & 2047;
                const float* cr = cosp + (size_t)s * 32;
                const float* sr = sinp + (size_t)s * 32;
                size_t base = ((size_t)(b * Hn + hh) * S_SZ + s) * 64;
#pragma unroll
                for (int nj = 0; nj < 2; nj++) {
                    int d = nj * 16 + c;          // 0..31
                    float x1 = acc[mi][nj][r];
                    float x2 = acc[mi][nj + 2][r];
                    float cv = cr[d], sv = sr[d];
                    dst[base + d]      = (bf16)((x1 * cv - x2 * sv) * sc);
                    dst[base + d + 32] = (bf16)((x1 * sv + x2 * cv) * sc);
                }
            }
        }
    } else {
        // ---- V path: transposed store (b, kv, d, s)
        const int kvh = (hcol >> 6) - 40;
        const int b   = mBase >> 11;
        const int s0  = mBase & 2047;
#pragma unroll
        for (int nj = 0; nj < 4; nj++) {
            int d = nj * 16 + c;
            size_t base = ((size_t)(b * KV_SZ + kvh) * 64 + d) * (size_t)S_SZ;
#pragma unroll
            for (int mi = 0; mi < 4; mi++) {
                int s = s0 + mi * 16 + quad * 4;
#pragma unroll
                for (int r = 0; r < 4; r++)
                    Vtb[base + s + r] = (bf16)acc[mi][nj][r];
            }
        }
    }
}

// ---------------------------------------------------------------- O-proj GEMM (fp32 out)
__global__ __launch_bounds__(256, 2)
void gemm_out(const bf16* __restrict__ A, const bf16* __restrict__ Bw,
              float* __restrict__ Co, int N, int K)
{
    __shared__ __align__(16) bf16 As[128 * 64];
    __shared__ __align__(16) bf16 Bs[128 * 64];

    GEMM_CORE4(A, Bw, K)

#pragma unroll
    for (int mi = 0; mi < 4; mi++)
#pragma unroll
        for (int ni = 0; ni < 4; ni++) {
            int col = nBase + ni * 16 + c;
#pragma unroll
            for (int r = 0; r < 4; r++) {
                int row = mBase + mi * 16 + quad * 4 + r;
                Co[(size_t)row * N + col] = acc[mi][ni][r];
            }
        }
}

// ---------------------------------------------------------------- flash attention
// v7: in-register P. QK^T (x32) leaves lane (c,quad) holding
// P[q=c][k = ni*16 + quad*4 + r] -- which is EXACTLY the B-operand layout of
// mfma_f32_16x16x16_bf16 (k = kblk*16 + quad*4 + i). So PV uses x16 MFMAs with
// P as bf16x4 registers: no P LDS write/read, no extra lgkm waits, Ps buffer
// freed (LDS 34.8K -> 18.4K). V^T x16 A-frag = bf16x4 read at
// Vs[(dblk*16+c)*72 + kblk*16 + quad*4]. C-layout of x16 == x32 -> oA/oB and
// epilogue unchanged. K/V rows stride 72 (144B = 9 bank-quads -> uniform
// bank-quad spread for both staging writes and frag reads; XOR swizzle dropped).
#define KVST 72   // K/V row stride (elems); 144B = 16B-aligned, bank-rotating

__global__ __launch_bounds__(256, 2)
void flash_attn(const bf16* __restrict__ Q, const bf16* __restrict__ Kc,
                const bf16* __restrict__ Vt, bf16* __restrict__ Aout)
{
    __shared__ __align__(16) bf16 Ks[64 * KVST];
    __shared__ __align__(16) bf16 Vs[64 * KVST];

    const int tid  = threadIdx.x;
    const int lane = tid & 63;
    const int wave = tid >> 6;
    const int c = lane & 15, quad = lane >> 4;
    const int qloc = wave * 16 + c;      // q index within 64-row tile

    const int i  = (blockIdx.x + blockIdx.y) & 15;   // balanced tile-pair index
    const int tA = 31 - i, tB = i;       // paired q-tiles (uniform 33 computes)
    const int q0A = tA << 6, q0B = tB << 6;

    const int bh = blockIdx.y;           // b*H + h
    const int b  = bh >> 5;
    const int h  = bh & 31;
    const int kv = h >> 2;

    const bf16* Qp = Q  + (size_t)bh * (S_SZ * 64);
    const bf16* Kp = Kc + (size_t)(b * KV_SZ + kv) * (S_SZ * 64);
    const bf16* Vp = Vt + (size_t)(b * KV_SZ + kv) * (64 * S_SZ);

    // Q fragments (x32 B-operand layout): n = lane&15, k = quad*8 (+32)
    bf16x8 aqA[2], aqB[2];
    {
        const bf16* qa = Qp + (size_t)(q0A + qloc) * 64 + quad * 8;
        aqA[0] = *(const bf16x8*)qa;  aqA[1] = *(const bf16x8*)(qa + 32);
        const bf16* qb = Qp + (size_t)(q0B + qloc) * 64 + quad * 8;
        aqB[0] = *(const bf16x8*)qb;  aqB[1] = *(const bf16x8*)(qb + 32);
    }

    f32x4 oA[4] = {}, oB[4] = {};
    f32x4 lA = {}, lB = {};

    bf16x4 ones4;
#pragma unroll
    for (int j = 0; j < 4; j++) ones4[j] = (bf16)1.0f;

    // staging: 256 threads cover 64x64 tile, 2 rows-of-16B each
    const int srow = tid >> 3;                 // 0..31
    const int ch   = tid & 7;                  // 16B chunk index
    const bf16* Kg0 = Kp + (size_t)srow * 64 + ch * 8;
    const bf16* Kg1 = Kp + (size_t)(srow + 32) * 64 + ch * 8;
    const bf16* Vg0 = Vp + (size_t)srow * S_SZ + ch * 8;
    const bf16* Vg1 = Vp + (size_t)(srow + 32) * S_SZ + ch * 8;

    uint4 pk0 = *(const uint4*)Kg0, pk1 = *(const uint4*)Kg1;
    uint4 pv0 = *(const uint4*)Vg0, pv1 = *(const uint4*)Vg1;

    for (int kt = 0; kt <= tA; kt++) {
        // stage current tile (regs loaded a full pass ago; vmcnt waited here)
        *(uint4*)(Ks + srow * KVST + ch * 8)        = pk0;
        *(uint4*)(Ks + (srow + 32) * KVST + ch * 8) = pk1;
        *(uint4*)(Vs + srow * KVST + ch * 8)        = pv0;
        *(uint4*)(Vs + (srow + 32) * KVST + ch * 8) = pv1;
        if (kt < tA) {   // issue next-tile prefetch; stays in flight across barriers
            pk0 = *(const uint4*)(Kg0 + (size_t)(kt + 1) * 4096);
            pk1 = *(const uint4*)(Kg1 + (size_t)(kt + 1) * 4096);
            pv0 = *(const uint4*)(Vg0 + (kt + 1) * 64);
            pv1 = *(const uint4*)(Vg1 + (kt + 1) * 64);
        }
        bar_lgkm();                        // stage writes visible; no vmcnt drain

        const bool doB   = (kt <= tB);
        const bool diagA = (kt == tA);
        const bool diagB = (kt == tB);

        // ---------------- QK^T for both tiles over shared K fragments (x32)
        f32x4 scA[4] = {}, scB[4] = {};
#pragma unroll
        for (int ks = 0; ks < 2; ks++) {
            bf16x8 ak4[4];
#pragma unroll
            for (int ni = 0; ni < 4; ni++)
                ak4[ni] = *(const bf16x8*)(Ks + (ni * 16 + c) * KVST
                                           + ((ks << 2) + quad) * 8);
            __builtin_amdgcn_s_setprio(1);
#pragma unroll
            for (int ni = 0; ni < 4; ni++)
                scA[ni] = __builtin_amdgcn_mfma_f32_16x16x32_bf16(ak4[ni], aqA[ks], scA[ni], 0, 0, 0);
            if (doB) {
#pragma unroll
                for (int ni = 0; ni < 4; ni++)
                    scB[ni] = __builtin_amdgcn_mfma_f32_16x16x32_bf16(ak4[ni], aqB[ks], scB[ni], 0, 0, 0);
            }
            __builtin_amdgcn_s_setprio(0);
        }

        // ---------------- softmax numerators -> registers (uniform diag branch)
        bf16x4 pA[4], pB[4];
        if (diagA) {
#pragma unroll
            for (int ni = 0; ni < 4; ni++)
#pragma unroll
                for (int r = 0; r < 4; r++) {
                    float p = exp2f(scA[ni][r]);
                    if ((ni * 16 + quad * 4 + r) > qloc) p = 0.f;
                    pA[ni][r] = (bf16)p;
                }
        } else {
#pragma unroll
            for (int ni = 0; ni < 4; ni++)
#pragma unroll
                for (int r = 0; r < 4; r++) pA[ni][r] = (bf16)exp2f(scA[ni][r]);
        }
        if (doB) {
            if (diagB) {
#pragma unroll
                for (int ni = 0; ni < 4; ni++)
#pragma unroll
                    for (int r = 0; r < 4; r++) {
                        float p = exp2f(scB[ni][r]);
                        if ((ni * 16 + quad * 4 + r) > qloc) p = 0.f;
                        pB[ni][r] = (bf16)p;
                    }
            } else {
#pragma unroll
                for (int ni = 0; ni < 4; ni++)
#pragma unroll
                    for (int r = 0; r < 4; r++) pB[ni][r] = (bf16)exp2f(scB[ni][r]);
            }
        }

        // ---------------- P @ V from registers (x16 MFMAs, shared V frags)
#pragma unroll
        for (int dblk = 0; dblk < 4; dblk++) {
            bf16x4 vf[4];
#pragma unroll
            for (int kb = 0; kb < 4; kb++)
                vf[kb] = *(const bf16x4*)(Vs + (dblk * 16 + c) * KVST
                                          + kb * 16 + quad * 4);
            __builtin_amdgcn_s_setprio(1);
#pragma unroll
            for (int kb = 0; kb < 4; kb++) {
                oA[dblk] = mfma16(vf[kb], pA[kb], oA[dblk]);
                if (doB) oB[dblk] = mfma16(vf[kb], pB[kb], oB[dblk]);
            }
            __builtin_amdgcn_s_setprio(0);
        }
#pragma unroll
        for (int kb = 0; kb < 4; kb++) {
            lA = mfma16(ones4, pA[kb], lA);
            if (doB) lB = mfma16(ones4, pB[kb], lB);
        }
        bar_lgkm();    // all waves' K/V reads done; next pass may overwrite
    }

    // epilogue: o[dblk][r] = O[q=c][d=dblk*16+quad*4+r]; packed 8B stores
    {
        float ila = 1.f / lA[0];
        float ilb = 1.f / lB[0];
        bf16* pa = Aout + ((size_t)(b * S_SZ + q0A + qloc)) * D_SZ + h * 64;
        bf16* pb = Aout + ((size_t)(b * S_SZ + q0B + qloc)) * D_SZ + h * 64;
#pragma unroll
        for (int ni = 0; ni < 4; ni++) {
            bf16x4 wa, wb;
#pragma unroll
            for (int r = 0; r < 4; r++) {
                wa[r] = (bf16)(oA[ni][r] * ila);
                wb[r] = (bf16)(oB[ni][r] * ilb);
            }
            *(bf16x4*)(pa + ni * 16 + quad * 4) = wa;
            *(bf16x4*)(pb + ni * 16 + quad * 4) = wb;
        }
    }
}

// ---------------------------------------------------------------- launcher
extern "C" void kernel_launch(void* const* d_in, const int* in_sizes, int n_in,
                              void* d_out, int out_size, void* d_ws, size_t ws_size,
                              hipStream_t stream) {
    const float* x    = (const float*)d_in[0];
    const float* cosp = (const float*)d_in[1];
    const float* sinp = (const float*)d_in[2];
    const float* Wq   = (const float*)d_in[3];
    const float* Wk   = (const float*)d_in[4];
    const float* Wv   = (const float*)d_in[5];
    const float* Wo   = (const float*)d_in[6];
    float* out = (float*)d_out;

    const int M = M_SZ;            // 4096
    const int D = D_SZ;            // 2048
    const int NKV = KV_SZ * HD_SZ; // 512

    // workspace layout (bf16 elems)
    bf16* xb   = (bf16*)d_ws;                    // M*D
    bf16* Wf   = xb  + (size_t)M * D;            // NQKV*D
    bf16* Qb   = Wf  + (size_t)NQKV * D;         // M*D (b,h,s,64)
    bf16* Kb   = Qb  + (size_t)M * D;            // (b,kv,s,64)
    bf16* Vtb  = Kb  + (size_t)B_SZ * KV_SZ * S_SZ * 64; // (b,kv,64,s)
    bf16* wob  = Vtb + (size_t)B_SZ * KV_SZ * 64 * S_SZ; // D*D
    bf16* attn = xb;    // alias: x dead after QKV GEMM

    const int nx = M * D / 4, n1 = D * D / 4, n2 = NKV * D / 4;

    // fused conversions (x + packed QKV weights + Wo)
    cvt_all<<<(nx + 2 * n1 + 2 * n2 + 255) / 256, 256, 0, stream>>>(
        x, Wq, Wk, Wv, Wo, xb, Wf, wob, nx, n1, n2);

    const float qscale = 0.125f * 1.44269504089f;   // 1/sqrt(hd) * log2(e)

    // fused QKV projection (+RoPE, +V transpose)
    gemm_qkv<<<dim3(NQKV / 128, M / 128), 256, 0, stream>>>(xb, Wf, Qb, Kb, Vtb, cosp, sinp, qscale);

    // flash attention -> attn (b,s,2048) bf16
    flash_attn<<<dim3(16, B_SZ * H_SZ), 256, 0, stream>>>(Qb, Kb, Vtb, attn);

    // out = attn Wo^T (fp32)
    gemm_out<<<dim3(D / 128, M / 128), 256, 0, stream>>>(attn, wob, out, D, D);
}

// Round 8
// 276.825 us; speedup vs baseline: 1.0661x; 1.0661x over previous
//
#include <hip/hip_runtime.h>
#include <hip/hip_bf16.h>

typedef __bf16 bf16;
typedef __attribute__((ext_vector_type(8))) __bf16 bf16x8;
typedef __attribute__((ext_vector_type(4))) __bf16 bf16x4;
typedef __attribute__((ext_vector_type(4))) float f32x4;

// ---------------------------------------------------------------- constants
#define B_SZ 2
#define S_SZ 2048
#define D_SZ 2048
#define H_SZ 32
#define KV_SZ 8
#define HD_SZ 64
#define M_SZ (B_SZ * S_SZ)   // 4096
#define NQKV 3072            // 2048 Q + 512 K + 512 V packed weight rows

// async global->LDS, 16B per lane; LDS dest = wave-uniform base + lane*16
#define GLDS(g, s) __builtin_amdgcn_global_load_lds( \
    (const __attribute__((address_space(1))) void*)(g), \
    (__attribute__((address_space(3))) void*)(s), 16, 0, 0)

// lgkm-only barrier: do NOT drain vmcnt (in-flight global_load_lds for the
// NEXT tile crosses the barrier; its completion is waited with a counted
// vmcnt at the top of the next iteration).
__device__ __forceinline__ void bar_lgkm() {
    asm volatile("s_waitcnt lgkmcnt(0)\n\ts_barrier" ::: "memory");
}

// ---------------------------------------------------------------- fused conversions
// single dispatch: x -> xb, [Wq;Wk;Wv] -> Wf, Wo -> wob (all bf16)
__global__ void cvt_all(const float* __restrict__ x, const float* __restrict__ Wq,
                        const float* __restrict__ Wk, const float* __restrict__ Wv,
                        const float* __restrict__ Wo,
                        bf16* __restrict__ xb, bf16* __restrict__ Wf, bf16* __restrict__ wob,
                        int nx, int n1, int n2) {
    int i = blockIdx.x * blockDim.x + threadIdx.x;
    const float* src; bf16* dst; int off;
    if (i < nx)                 { src = x;  dst = xb; off = i; }
    else {
        int j = i - nx;
        if (j < n1)             { src = Wq; dst = Wf; off = j; }
        else if (j < n1 + n2)   { src = Wk; dst = Wf + (size_t)4 * n1; off = j - n1; }
        else if (j < n1 + 2*n2) { src = Wv; dst = Wf + (size_t)4 * (n1 + n2); off = j - n1 - n2; }
        else if (j < 2*n1+2*n2) { src = Wo; dst = wob; off = j - n1 - 2 * n2; }
        else return;
    }
    float4 v = ((const float4*)src)[off];
    bf16x4 o;
    o.x = (bf16)v.x; o.y = (bf16)v.y; o.z = (bf16)v.z; o.w = (bf16)v.w;
    ((bf16x4*)dst)[off] = o;
}

// ---------------------------------------------------------------- GEMM core v4: 2-phase dbuf
// 256 threads / 4 waves; wave (wr,wc) owns the 64x64 quadrant; acc[4][4].
// T3-minimum pipeline: LDS double buffer (2 x 32KB). Next tile's 8
// global_load_lds per wave are issued BEFORE computing the current tile and
// stay in flight across the trailing lgkm-only barrier; the head of the next
// iteration waits vmcnt(8) (own-tile loads done, next-tile loads still
// outstanding) -- never vmcnt(0) in the main loop (T4 counted-vmcnt).
// XOR chunk swizzle (chunk q of row r at q^(r&7)); staging lane l fetches
// global chunk (l&7)^(l>>3) so LDS writes are linear; b128 reads conflict-free.
#define GEMM_CORE5(A_, B_, Kdim)                                                 \
    const int tid  = threadIdx.x;                                                \
    const int wv   = tid >> 6;                                                   \
    const int lane = tid & 63;                                                   \
    const int c = lane & 15, quad = lane >> 4;                                   \
    const int wr = wv >> 1, wc = wv & 1;                                         \
    const int g8 = lane >> 3;                                                    \
    const int chs = ((lane & 7) ^ g8) * 8;                                       \
    const int rowBase = blockIdx.y * 128;                                        \
    const int colBase = blockIdx.x * 128;                                        \
    const bf16* Ag = A_ + (size_t)(rowBase + wv * 32 + g8) * Kdim + chs;         \
    const bf16* Bg = B_ + (size_t)(colBase + wv * 32 + g8) * Kdim + chs;         \
    f32x4 acc[4][4] = {};                                                        \
    _Pragma("unroll")                                                            \
    for (int j = 0; j < 4; j++) {       /* prologue: stage tile 0 -> buf 0 */    \
        GLDS(Ag + (size_t)(j * 8) * Kdim, Ls + (wv * 32 + j * 8) * 64);          \
        GLDS(Bg + (size_t)(j * 8) * Kdim, Ls + 8192 + (wv * 32 + j * 8) * 64);   \
    }                                                                            \
    for (int k0 = 0; k0 < Kdim; k0 += 64) {                                      \
        bf16* Asb = Ls + ((k0 >> 6) & 1) * 16384;                                \
        bf16* Bsb = Asb + 8192;                                                  \
        if (k0 + 64 < Kdim) {           /* issue next tile into other buf */     \
            bf16* Asn = Ls + ((((k0 >> 6) & 1) ^ 1) * 16384);                    \
            _Pragma("unroll")                                                    \
            for (int j = 0; j < 4; j++) {                                        \
                GLDS(Ag + (size_t)(j * 8) * Kdim + (k0 + 64),                    \
                     Asn + (wv * 32 + j * 8) * 64);                              \
                GLDS(Bg + (size_t)(j * 8) * Kdim + (k0 + 64),                    \
                     Asn + 8192 + (wv * 32 + j * 8) * 64);                       \
            }                                                                    \
            asm volatile("s_waitcnt vmcnt(8)" ::: "memory");                     \
        } else {                                                                 \
            asm volatile("s_waitcnt vmcnt(0)" ::: "memory");                     \
        }                                                                        \
        asm volatile("s_waitcnt lgkmcnt(0)\n\ts_barrier" ::: "memory");          \
        _Pragma("unroll")                                                        \
        for (int ks = 0; ks < 2; ks++) {                                         \
            bf16x8 af[4], bfr[4];                                                \
            _Pragma("unroll")                                                    \
            for (int mi = 0; mi < 4; mi++)                                       \
                af[mi] = *(const bf16x8*)(Asb + (wr * 64 + mi * 16 + c) * 64     \
                                          + (((ks << 2) + quad) ^ (c & 7)) * 8); \
            _Pragma("unroll")                                                    \
            for (int ni = 0; ni < 4; ni++)                                       \
                bfr[ni] = *(const bf16x8*)(Bsb + (wc * 64 + ni * 16 + c) * 64    \
                                          + (((ks << 2) + quad) ^ (c & 7)) * 8); \
            _Pragma("unroll")                                                    \
            for (int mi = 0; mi < 4; mi++)                                       \
                _Pragma("unroll")                                                \
                for (int ni = 0; ni < 4; ni++)                                   \
                    acc[mi][ni] = __builtin_amdgcn_mfma_f32_16x16x32_bf16(       \
                        af[mi], bfr[ni], acc[mi][ni], 0, 0, 0);                  \
        }                                                                        \
        asm volatile("s_waitcnt lgkmcnt(0)\n\ts_barrier" ::: "memory");          \
    }                                                                            \
    const int mBase = rowBase + wr * 64;                                         \
    const int nBase = colBase + wc * 64;

// ---------------------------------------------------------------- fused QKV GEMM
__global__ __launch_bounds__(256, 2)
void gemm_qkv(const bf16* __restrict__ A, const bf16* __restrict__ Bw,
              bf16* __restrict__ Qb, bf16* __restrict__ Kb, bf16* __restrict__ Vtb,
              const float* __restrict__ cosp, const float* __restrict__ sinp,
              float qscale)
{
    __shared__ __align__(16) bf16 Ls[2 * 16384];   // 64KB: 2 x (A 16K + B 16K)

    GEMM_CORE5(A, Bw, D_SZ)

    // wave's 64 cols = exactly one 64-wide head; Q/K/V regions are 64-aligned
    const int hcol = nBase;
    if (hcol < 2560) {
        // ---- RoPE path (Q or K)
        bf16* dst; int hh, Hn; float sc;
        if (hcol < 2048) { dst = Qb; hh = hcol >> 6;        Hn = H_SZ;  sc = qscale; }
        else             { dst = Kb; hh = (hcol >> 6) - 32; Hn = KV_SZ; sc = 1.0f;  }
#pragma unroll
        for (int mi = 0; mi < 4; mi++) {
#pragma unroll
            for (int r = 0; r < 4; r++) {
                int row = mBase + mi * 16 + quad * 4 + r;
                int b = row >> 11;           // S = 2048
                int s = row & 2047;
                const float* cr = cosp + (size_t)s * 32;
                const float* sr = sinp + (size_t)s * 32;
                size_t base = ((size_t)(b * Hn + hh) * S_SZ + s) * 64;
#pragma unroll
                for (int nj = 0; nj < 2; nj++) {
                    int d = nj * 16 + c;          // 0..31
                    float x1 = acc[mi][nj][r];
                    float x2 = acc[mi][nj + 2][r];
                    float cv = cr[d], sv = sr[d];
                    dst[base + d]      = (bf16)((x1 * cv - x2 * sv) * sc);
                    dst[base + d + 32] = (bf16)((x1 * sv + x2 * cv) * sc);
                }
            }
        }
    } else {
        // ---- V path: transposed store (b, kv, d, s)
        const int kvh = (hcol >> 6) - 40;
        const int b   = mBase >> 11;
        const int s0  = mBase & 2047;
#pragma unroll
        for (int nj = 0; nj < 4; nj++) {
            int d = nj * 16 + c;
            size_t base = ((size_t)(b * KV_SZ + kvh) * 64 + d) * (size_t)S_SZ;
#pragma unroll
            for (int mi = 0; mi < 4; mi++) {
                int s = s0 + mi * 16 + quad * 4;
#pragma unroll
                for (int r = 0; r < 4; r++)
                    Vtb[base + s + r] = (bf16)acc[mi][nj][r];
            }
        }
    }
}

// ---------------------------------------------------------------- O-proj GEMM (fp32 out)
__global__ __launch_bounds__(256, 2)
void gemm_out(const bf16* __restrict__ A, const bf16* __restrict__ Bw,
              float* __restrict__ Co, int N, int K)
{
    __shared__ __align__(16) bf16 Ls[2 * 16384];   // 64KB

    GEMM_CORE5(A, Bw, K)

#pragma unroll
    for (int mi = 0; mi < 4; mi++)
#pragma unroll
        for (int ni = 0; ni < 4; ni++) {
            int col = nBase + ni * 16 + c;
#pragma unroll
            for (int r = 0; r < 4; r++) {
                int row = mBase + mi * 16 + quad * 4 + r;
                Co[(size_t)row * N + col] = acc[mi][ni][r];
            }
        }
}

// ---------------------------------------------------------------- flash attention
// v5 structure reverted (proven 81us): 16 q-rows/wave, 64-row tiles A/B,
// P staged through LDS (x32 PV), XOR-swizzled K/V tiles, 34816B LDS,
// lgkm-only barriers, balanced tile-pair index.
#define PST 72   // P row stride (elems); 2-way bank alias on b64/b128 = free

__global__ __launch_bounds__(256, 3)
void flash_attn(const bf16* __restrict__ Q, const bf16* __restrict__ Kc,
                const bf16* __restrict__ Vt, bf16* __restrict__ Aout)
{
    __shared__ __align__(16) bf16 Ks[64 * 64];
    __shared__ __align__(16) bf16 Vs[64 * 64];
    __shared__ __align__(16) bf16 Ps[2 * 4 * 16 * PST];

    const int tid  = threadIdx.x;
    const int lane = tid & 63;
    const int wave = tid >> 6;
    const int c = lane & 15, quad = lane >> 4;
    const int qloc = wave * 16 + c;      // q index within 64-row tile

    const int i  = (blockIdx.x + blockIdx.y) & 15;   // balanced tile-pair index
    const int tA = 31 - i, tB = i;       // paired q-tiles (uniform 33 computes)
    const int q0A = tA << 6, q0B = tB << 6;

    const int bh = blockIdx.y;           // b*H + h
    const int b  = bh >> 5;
    const int h  = bh & 31;
    const int kv = h >> 2;

    const bf16* Qp = Q  + (size_t)bh * (S_SZ * 64);
    const bf16* Kp = Kc + (size_t)(b * KV_SZ + kv) * (S_SZ * 64);
    const bf16* Vp = Vt + (size_t)(b * KV_SZ + kv) * (64 * S_SZ);

    // Q fragments (B-operand layout): n = lane&15, k = quad*8 (+32)
    bf16x8 aqA[2], aqB[2];
    {
        const bf16* qa = Qp + (size_t)(q0A + qloc) * 64 + quad * 8;
        aqA[0] = *(const bf16x8*)qa;  aqA[1] = *(const bf16x8*)(qa + 32);
        const bf16* qb = Qp + (size_t)(q0B + qloc) * 64 + quad * 8;
        aqB[0] = *(const bf16x8*)qb;  aqB[1] = *(const bf16x8*)(qb + 32);
    }

    f32x4 oA[4] = {}, oB[4] = {};
    f32x4 lA = {}, lB = {};

    bf16x8 ones;
#pragma unroll
    for (int j = 0; j < 8; j++) ones[j] = (bf16)1.0f;

    // staging: 256 threads cover 64x64 tile, 2 rows-of-16B each; XOR swizzle
    const int srow = tid >> 3;                 // 0..31
    const int ch   = tid & 7;                  // global 16B chunk index
    const int sws  = (ch ^ (srow & 7)) * 8;    // swizzled LDS chunk offset (elems)
    const bf16* Kg0 = Kp + (size_t)srow * 64 + ch * 8;
    const bf16* Kg1 = Kp + (size_t)(srow + 32) * 64 + ch * 8;
    const bf16* Vg0 = Vp + (size_t)srow * S_SZ + ch * 8;
    const bf16* Vg1 = Vp + (size_t)(srow + 32) * S_SZ + ch * 8;

    uint4 pk0 = *(const uint4*)Kg0, pk1 = *(const uint4*)Kg1;
    uint4 pv0 = *(const uint4*)Vg0, pv1 = *(const uint4*)Vg1;

    bf16* PwA = Ps + wave * 16 * PST;
    bf16* PwB = Ps + (4 + wave) * 16 * PST;

    for (int kt = 0; kt <= tA; kt++) {
        // stage current tile (regs loaded a full pass ago; vmcnt waited here)
        *(uint4*)(Ks + srow * 64 + sws)        = pk0;
        *(uint4*)(Ks + (srow + 32) * 64 + sws) = pk1;   // (srow+32)&7 == srow&7
        *(uint4*)(Vs + srow * 64 + sws)        = pv0;
        *(uint4*)(Vs + (srow + 32) * 64 + sws) = pv1;
        if (kt < tA) {   // issue next-tile prefetch; stays in flight across barriers
            pk0 = *(const uint4*)(Kg0 + (size_t)(kt + 1) * 4096);
            pk1 = *(const uint4*)(Kg1 + (size_t)(kt + 1) * 4096);
            pv0 = *(const uint4*)(Vg0 + (kt + 1) * 64);
            pv1 = *(const uint4*)(Vg1 + (kt + 1) * 64);
        }
        bar_lgkm();                        // stage writes visible; no vmcnt drain

        const bool doB   = (kt <= tB);
        const bool diagA = (kt == tA);
        const bool diagB = (kt == tB);

        // ---------------- QK^T for both tiles over shared K fragments
        f32x4 scA[4] = {}, scB[4] = {};
#pragma unroll
        for (int ks = 0; ks < 2; ks++) {
            bf16x8 ak4[4];
#pragma unroll
            for (int ni = 0; ni < 4; ni++)
                ak4[ni] = *(const bf16x8*)(Ks + (ni * 16 + c) * 64
                                           + (((ks << 2) + quad) ^ (c & 7)) * 8);
            __builtin_amdgcn_s_setprio(1);
#pragma unroll
            for (int ni = 0; ni < 4; ni++)
                scA[ni] = __builtin_amdgcn_mfma_f32_16x16x32_bf16(ak4[ni], aqA[ks], scA[ni], 0, 0, 0);
            if (doB) {
#pragma unroll
                for (int ni = 0; ni < 4; ni++)
                    scB[ni] = __builtin_amdgcn_mfma_f32_16x16x32_bf16(ak4[ni], aqB[ks], scB[ni], 0, 0, 0);
            }
            __builtin_amdgcn_s_setprio(0);
        }

        // ---------------- softmax numerators -> P (uniform diag branch)
        if (diagA) {
#pragma unroll
            for (int ni = 0; ni < 4; ni++) {
                bf16x4 pk;
#pragma unroll
                for (int r = 0; r < 4; r++) {
                    float p = exp2f(scA[ni][r]);
                    if ((ni * 16 + quad * 4 + r) > qloc) p = 0.f;
                    pk[r] = (bf16)p;
                }
                *(bf16x4*)(PwA + c * PST + ni * 16 + quad * 4) = pk;
            }
        } else {
#pragma unroll
            for (int ni = 0; ni < 4; ni++) {
                bf16x4 pk;
#pragma unroll
                for (int r = 0; r < 4; r++) pk[r] = (bf16)exp2f(scA[ni][r]);
                *(bf16x4*)(PwA + c * PST + ni * 16 + quad * 4) = pk;
            }
        }
        if (doB) {
            if (diagB) {
#pragma unroll
                for (int ni = 0; ni < 4; ni++) {
                    bf16x4 pk;
#pragma unroll
                    for (int r = 0; r < 4; r++) {
                        float p = exp2f(scB[ni][r]);
                        if ((ni * 16 + quad * 4 + r) > qloc) p = 0.f;
                        pk[r] = (bf16)p;
                    }
                    *(bf16x4*)(PwB + c * PST + ni * 16 + quad * 4) = pk;
                }
            } else {
#pragma unroll
                for (int ni = 0; ni < 4; ni++) {
                    bf16x4 pk;
#pragma unroll
                    for (int r = 0; r < 4; r++) pk[r] = (bf16)exp2f(scB[ni][r]);
                    *(bf16x4*)(PwB + c * PST + ni * 16 + quad * 4) = pk;
                }
            }
        }

        // ---------------- P @ V for both tiles over shared V fragments
#pragma unroll
        for (int ks = 0; ks < 2; ks++) {
            bf16x8 av4[4];
#pragma unroll
            for (int ni = 0; ni < 4; ni++)
                av4[ni] = *(const bf16x8*)(Vs + (ni * 16 + c) * 64
                                           + (((ks << 2) + quad) ^ (c & 7)) * 8);
            bf16x8 bpA = *(const bf16x8*)(PwA + c * PST + ks * 32 + quad * 8);
            __builtin_amdgcn_s_setprio(1);
            lA = __builtin_amdgcn_mfma_f32_16x16x32_bf16(ones, bpA, lA, 0, 0, 0);
#pragma unroll
            for (int ni = 0; ni < 4; ni++)
                oA[ni] = __builtin_amdgcn_mfma_f32_16x16x32_bf16(av4[ni], bpA, oA[ni], 0, 0, 0);
            __builtin_amdgcn_s_setprio(0);
            if (doB) {
                bf16x8 bpB = *(const bf16x8*)(PwB + c * PST + ks * 32 + quad * 8);
                __builtin_amdgcn_s_setprio(1);
                lB = __builtin_amdgcn_mfma_f32_16x16x32_bf16(ones, bpB, lB, 0, 0, 0);
#pragma unroll
                for (int ni = 0; ni < 4; ni++)
                    oB[ni] = __builtin_amdgcn_mfma_f32_16x16x32_bf16(av4[ni], bpB, oB[ni], 0, 0, 0);
                __builtin_amdgcn_s_setprio(0);
            }
        }
        bar_lgkm();    // all waves' K/V/P reads done; next pass may overwrite
    }

    // epilogue: o[ni][r] = O[q=c][d=ni*16+quad*4+r]; packed 8B stores
    {
        float ila = 1.f / lA[0];
        float ilb = 1.f / lB[0];
        bf16* pa = Aout + ((size_t)(b * S_SZ + q0A + qloc)) * D_SZ + h * 64;
        bf16* pb = Aout + ((size_t)(b * S_SZ + q0B + qloc)) * D_SZ + h * 64;
#pragma unroll
        for (int ni = 0; ni < 4; ni++) {
            bf16x4 wa, wb;
#pragma unroll
            for (int r = 0; r < 4; r++) {
                wa[r] = (bf16)(oA[ni][r] * ila);
                wb[r] = (bf16)(oB[ni][r] * ilb);
            }
            *(bf16x4*)(pa + ni * 16 + quad * 4) = wa;
            *(bf16x4*)(pb + ni * 16 + quad * 4) = wb;
        }
    }
}

// ---------------------------------------------------------------- launcher
extern "C" void kernel_launch(void* const* d_in, const int* in_sizes, int n_in,
                              void* d_out, int out_size, void* d_ws, size_t ws_size,
                              hipStream_t stream) {
    const float* x    = (const float*)d_in[0];
    const float* cosp = (const float*)d_in[1];
    const float* sinp = (const float*)d_in[2];
    const float* Wq   = (const float*)d_in[3];
    const float* Wk   = (const float*)d_in[4];
    const float* Wv   = (const float*)d_in[5];
    const float* Wo   = (const float*)d_in[6];
    float* out = (float*)d_out;

    const int M = M_SZ;            // 4096
    const int D = D_SZ;            // 2048
    const int NKV = KV_SZ * HD_SZ; // 512

    // workspace layout (bf16 elems)
    bf16* xb   = (bf16*)d_ws;                    // M*D
    bf16* Wf   = xb  + (size_t)M * D;            // NQKV*D
    bf16* Qb   = Wf  + (size_t)NQKV * D;         // M*D (b,h,s,64)
    bf16* Kb   = Qb  + (size_t)M * D;            // (b,kv,s,64)
    bf16* Vtb  = Kb  + (size_t)B_SZ * KV_SZ * S_SZ * 64; // (b,kv,64,s)
    bf16* wob  = Vtb + (size_t)B_SZ * KV_SZ * 64 * S_SZ; // D*D
    bf16* attn = xb;    // alias: x dead after QKV GEMM

    const int nx = M * D / 4, n1 = D * D / 4, n2 = NKV * D / 4;

    // fused conversions (x + packed QKV weights + Wo)
    cvt_all<<<(nx + 2 * n1 + 2 * n2 + 255) / 256, 256, 0, stream>>>(
        x, Wq, Wk, Wv, Wo, xb, Wf, wob, nx, n1, n2);

    const float qscale = 0.125f * 1.44269504089f;   // 1/sqrt(hd) * log2(e)

    // fused QKV projection (+RoPE, +V transpose)
    gemm_qkv<<<dim3(NQKV / 128, M / 128), 256, 0, stream>>>(xb, Wf, Qb, Kb, Vtb, cosp, sinp, qscale);

    // flash attention -> attn (b,s,2048) bf16
    flash_attn<<<dim3(16, B_SZ * H_SZ), 256, 0, stream>>>(Qb, Kb, Vtb, attn);

    // out = attn Wo^T (fp32)
    gemm_out<<<dim3(D / 128, M / 128), 256, 0, stream>>>(attn, wob, out, D, D);
}